// Round 8
// baseline (138.083 us; speedup 1.0000x reference)
//
#include <hip/hip_runtime.h>
#include <hip/hip_fp16.h>
#include <math.h>

#define B_  16
#define H_  8
#define L_  512
#define DM_ 512
#define DK_ 64
#define LOG2E_ 1.44269504088896340736f
#define NLOG2E_H_ 0.72134752044f   // 0.5 * log2(e)

typedef _Float16 f16;
typedef __attribute__((ext_vector_type(2)))  __fp16   fp16v2;
typedef __attribute__((ext_vector_type(8)))  _Float16 f16x8;
typedef __attribute__((ext_vector_type(16))) float f32x16;

__device__ __forceinline__ unsigned pkrtz(float a, float b) {
    union { fp16v2 v; unsigned u; } cv;
    cv.v = __builtin_amdgcn_cvt_pkrtz(a, b);
    return cv.u;
}
// v_permlane32_swap_b32: x[lanes 32..63] <-> y[lanes 0..31]
__device__ __forceinline__ void plswap(unsigned &x, unsigned &y) {
    asm("v_permlane32_swap_b32 %0, %1" : "+v"(x), "+v"(y));
}

// ---------------------------------------------------------------------------
// MFMA fp16 GEMM core:  Y = X[M,512] @ W[512,512]^T + bias
// BM=128, BN=64, BK=64; 256 threads = 4 waves (2 row-blocks x 2 col-blocks).
// Reg-staged fp32->fp16 conversion; LDS XOR-swizzled; next-tile prefetch.
// TRANSOUT: C^T via swapped operands -> store V^T [(b*512+n)][l].
// Caller passes decoded row0/col0 (XCD-chunked grid).
// ---------------------------------------------------------------------------
template<int XF16, int OUTF32, int TRANSOUT>
__device__ __forceinline__ void gemm_core(
    const void* __restrict__ Xv, const float* __restrict__ W,
    const float* __restrict__ bias, void* __restrict__ Yv,
    int row0, int col0, f16* lds)
{
    f16* Al = lds;                 // 128 x 64 fp16
    f16* Bl = lds + 128 * 64;      // 64 x 64 fp16

    const int tid   = threadIdx.x;
    const int w     = tid >> 6;
    const int lane  = tid & 63;
    const int lq    = lane & 31;
    const int half_ = lane >> 5;
    const int wa    = w & 1;       // row-64 block (trans: l-64 block)
    const int wb    = w >> 1;      // col-32 block (trans: n-32 block)
    const int xrow  = tid >> 1;    // 0..127
    const int xseg  = tid & 1;     // k half (32 floats)
    const int wrow  = tid >> 2;    // 0..63
    const int wseg  = tid & 3;     // k quarter (16 floats)

    f32x16 acc[2];
    #pragma unroll
    for (int rs = 0; rs < 2; ++rs)
        #pragma unroll
        for (int i = 0; i < 16; ++i) acc[rs][i] = 0.f;

    float4 xr[8], wreg[4];
    uint4  xh[4];

    // prologue: load tile 0
    {
        if (XF16) {
            const f16* X = (const f16*)Xv;
            const f16* p = X + (size_t)(row0 + xrow) * 512 + xseg * 32;
            #pragma unroll
            for (int j = 0; j < 4; ++j) xh[j] = *(const uint4*)(p + j * 8);
        } else {
            const float* X = (const float*)Xv;
            const float* p = X + (size_t)(row0 + xrow) * 512 + xseg * 32;
            #pragma unroll
            for (int j = 0; j < 8; ++j) xr[j] = *(const float4*)(p + j * 4);
        }
        const float* q = W + (size_t)(col0 + wrow) * 512 + wseg * 16;
        #pragma unroll
        for (int j = 0; j < 4; ++j) wreg[j] = *(const float4*)(q + j * 4);
    }

    for (int t = 0; t < 8; ++t) {
        __syncthreads();
        // staged regs -> LDS (swizzled)
        {
            uint4 c[4];
            if (XF16) {
                c[0] = xh[0]; c[1] = xh[1]; c[2] = xh[2]; c[3] = xh[3];
            } else {
                #pragma unroll
                for (int j = 0; j < 4; ++j) {
                    c[j].x = pkrtz(xr[2*j].x, xr[2*j].y);
                    c[j].y = pkrtz(xr[2*j].z, xr[2*j].w);
                    c[j].z = pkrtz(xr[2*j+1].x, xr[2*j+1].y);
                    c[j].w = pkrtz(xr[2*j+1].z, xr[2*j+1].w);
                }
            }
            const unsigned xbase = xrow * 128 + xseg * 64;
            const unsigned xswz  = (xrow & 7) << 4;
            #pragma unroll
            for (int j = 0; j < 4; ++j)
                *(uint4*)((char*)Al + ((xbase + 16 * j) ^ xswz)) = c[j];

            uint4 d0, d1;
            d0.x = pkrtz(wreg[0].x, wreg[0].y); d0.y = pkrtz(wreg[0].z, wreg[0].w);
            d0.z = pkrtz(wreg[1].x, wreg[1].y); d0.w = pkrtz(wreg[1].z, wreg[1].w);
            d1.x = pkrtz(wreg[2].x, wreg[2].y); d1.y = pkrtz(wreg[2].z, wreg[2].w);
            d1.z = pkrtz(wreg[3].x, wreg[3].y); d1.w = pkrtz(wreg[3].z, wreg[3].w);
            const unsigned wbase = wrow * 128 + wseg * 32;
            const unsigned wswz  = (wrow & 7) << 4;
            *(uint4*)((char*)Bl + ((wbase +  0) ^ wswz)) = d0;
            *(uint4*)((char*)Bl + ((wbase + 16) ^ wswz)) = d1;
        }
        __syncthreads();

        // prefetch next tile
        if (t < 7) {
            const int k0 = (t + 1) * 64;
            if (XF16) {
                const f16* X = (const f16*)Xv;
                const f16* p = X + (size_t)(row0 + xrow) * 512 + k0 + xseg * 32;
                #pragma unroll
                for (int j = 0; j < 4; ++j) xh[j] = *(const uint4*)(p + j * 8);
            } else {
                const float* X = (const float*)Xv;
                const float* p = X + (size_t)(row0 + xrow) * 512 + k0 + xseg * 32;
                #pragma unroll
                for (int j = 0; j < 8; ++j) xr[j] = *(const float4*)(p + j * 4);
            }
            const float* q = W + (size_t)(col0 + wrow) * 512 + k0 + wseg * 16;
            #pragma unroll
            for (int j = 0; j < 4; ++j) wreg[j] = *(const float4*)(q + j * 4);
        }

        // MFMAs on current tile
        #pragma unroll
        for (int ks = 0; ks < 4; ++ks) {
            const unsigned koff = ks * 32 + half_ * 16;
            if (TRANSOUT) {
                const int rn = wb * 32 + lq;          // W row (n)
                const int rl0 = wa * 64 + lq;         // X rows (l)
                const int rl1 = wa * 64 + 32 + lq;
                f16x8 aw = *(const f16x8*)((char*)Bl + ((rn  * 128 + koff) ^ ((rn  & 7) << 4)));
                f16x8 b0 = *(const f16x8*)((char*)Al + ((rl0 * 128 + koff) ^ ((rl0 & 7) << 4)));
                f16x8 b1 = *(const f16x8*)((char*)Al + ((rl1 * 128 + koff) ^ ((rl1 & 7) << 4)));
                acc[0] = __builtin_amdgcn_mfma_f32_32x32x16_f16(aw, b0, acc[0], 0, 0, 0);
                acc[1] = __builtin_amdgcn_mfma_f32_32x32x16_f16(aw, b1, acc[1], 0, 0, 0);
            } else {
                const int ra0 = wa * 64 + lq;         // X rows
                const int ra1 = wa * 64 + 32 + lq;
                const int rbc = wb * 32 + lq;         // W row (col)
                f16x8 a0 = *(const f16x8*)((char*)Al + ((ra0 * 128 + koff) ^ ((ra0 & 7) << 4)));
                f16x8 a1 = *(const f16x8*)((char*)Al + ((ra1 * 128 + koff) ^ ((ra1 & 7) << 4)));
                f16x8 bf = *(const f16x8*)((char*)Bl + ((rbc * 128 + koff) ^ ((rbc & 7) << 4)));
                acc[0] = __builtin_amdgcn_mfma_f32_32x32x16_f16(a0, bf, acc[0], 0, 0, 0);
                acc[1] = __builtin_amdgcn_mfma_f32_32x32x16_f16(a1, bf, acc[1], 0, 0, 0);
            }
        }
    }

    if (TRANSOUT) {
        // acc[s][r]: n = col0 + wb*32 + crow(r), l = row0 + wa*64 + s*32 + lq
        #pragma unroll
        for (int s = 0; s < 2; ++s) {
            const int lg = row0 + wa * 64 + s * 32 + lq;
            const int bI = lg >> 9, ll = lg & 511;
            #pragma unroll
            for (int r = 0; r < 16; ++r) {
                const int n = col0 + wb * 32 + (r & 3) + 8 * (r >> 2) + 4 * half_;
                const float v = acc[s][r] + bias[n];
                ((f16*)Yv)[((size_t)(bI * 512 + n)) * 512 + ll] = (f16)v;
            }
        }
    } else {
        const float bv = bias[col0 + wb * 32 + lq];
        #pragma unroll
        for (int s = 0; s < 2; ++s) {
            #pragma unroll
            for (int r = 0; r < 16; ++r) {
                const int row = row0 + wa * 64 + s * 32 + (r & 3) + 8 * (r >> 2) + 4 * half_;
                const float v = acc[s][r] + bv;
                const size_t off = (size_t)row * 512 + col0 + wb * 32 + lq;
                if (OUTF32) ((float*)Yv)[off] = v;
                else        ((f16*)Yv)[off]   = (f16)v;
            }
        }
    }
}

// fused Q/K/V projections, XCD-chunked 1-D grid (1536 blocks).
// wg -> xcd = wg&7; idx = wg>>3; col = idx&7; pp = idx>>3;
// panel = xcd*24 + pp; z = panel>>6; y = panel&63.
// All 8 col-blocks of an X panel dispatch consecutively on ONE XCD.
__global__ __launch_bounds__(256) void gemm_qkv(
    const float* __restrict__ query, const float* __restrict__ key,
    const float* __restrict__ value,
    const float* __restrict__ Wq, const float* __restrict__ bq,
    const float* __restrict__ Wk, const float* __restrict__ bk,
    const float* __restrict__ Wv, const float* __restrict__ bv,
    void* __restrict__ Qb, void* __restrict__ Kb, void* __restrict__ VT)
{
    __shared__ f16 lds[(128 + 64) * 64];
    const int wg  = blockIdx.x;
    const int xcd = wg & 7;
    const int idx = wg >> 3;
    const int col = idx & 7;
    const int pp  = idx >> 3;
    const int pg  = xcd * 24 + pp;      // 0..191
    const int z   = pg >> 6;
    const int y   = pg & 63;
    const int row0 = y * 128, col0 = col * 64;

    if (z == 0)      gemm_core<0, 0, 0>(query, Wq, bq, Qb, row0, col0, lds);
    else if (z == 1) gemm_core<0, 0, 0>(key,   Wk, bk, Kb, row0, col0, lds);
    else             gemm_core<0, 0, 1>(value, Wv, bv, VT, row0, col0, lds);
}

// output GEMM, XCD-chunked 1-D grid (512 blocks): y = xcd*8 + (idx>>3)
__global__ __launch_bounds__(256) void gemm_o(
    const void* __restrict__ X, const float* __restrict__ Wo,
    const float* __restrict__ bo, void* __restrict__ Y)
{
    __shared__ f16 lds[(128 + 64) * 64];
    const int wg  = blockIdx.x;
    const int xcd = wg & 7;
    const int idx = wg >> 3;
    const int col = idx & 7;
    const int y   = xcd * 8 + (idx >> 3);
    gemm_core<1, 1, 0>(X, Wo, bo, Y, y * 128, col * 64, lds);
}

// ---------------------------------------------------------------------------
// Split-K zero-staging MFMA flash attention (unchanged from R7).
// ---------------------------------------------------------------------------
__global__ __launch_bounds__(128) void attn_kernel(
    const f16* __restrict__ Q, const f16* __restrict__ K,
    const f16* __restrict__ VT, const float* __restrict__ Wg,
    const float* __restrict__ bg, const float* __restrict__ lam1,
    f16* __restrict__ ATT)
{
    __shared__ float Lm[64], Lss[64], Lsa[64];
    __shared__ float Lacc[4][16][64];

    const int tid  = threadIdx.x;
    const int ws   = tid >> 6;        // split-K wave id (0,1)
    const int lane = tid & 63;
    const int lq   = lane & 31;
    const int half = lane >> 5;
    const int bh   = blockIdx.x;      // same bh -> same XCD
    const int b    = bh >> 3;
    const int h    = bh & 7;
    const int q0w  = blockIdx.y * 32;
    const int q    = q0w + lq;

    const float sg  = 1.f / (1.f + __expf(-lam1[0]));
    const float osg = 1.f - sg;

    f16x8 qh[4];
    {
        const f16* qrow = Q + ((size_t)(b * L_ + q) * DM_ + h * DK_);
        #pragma unroll
        for (int db = 0; db < 4; ++db)
            qh[db] = *(const f16x8*)&qrow[db * 16 + 8 * half];
    }

    float A0, A1, qpw;
    {
        float g0 = 0.f, g1 = 0.f;
        #pragma unroll
        for (int db = 0; db < 4; ++db)
            #pragma unroll
            for (int j = 0; j < 8; ++j) {
                const int d = db * 16 + 8 * half + j;
                const float qv = (float)qh[db][j];
                g0 = fmaf(qv, Wg[d], g0);
                g1 = fmaf(qv, Wg[64 + d], g1);
            }
        g0 += __shfl_xor(g0, 32);
        g1 += __shfl_xor(g1, 32);
        g0 += bg[0];
        g1 += bg[1];
        const float t0 = fabsf(g0) + 1.f, t1 = fabsf(g1) + 1.f;
        const float p0 = 1.f / (t0 * t0), p1 = 1.f / (t1 * t1);
        A0 = -NLOG2E_H_ * p0;       // c >= q (triu)
        A1 = -NLOG2E_H_ * p1;       // c <  q (tril)
        float mn = NLOG2E_H_ * fminf(p0, p1);
        #pragma unroll
        for (int off = 1; off < 64; off <<= 1) mn = fminf(mn, __shfl_xor(mn, off));
        qpw = mn;
    }

    f32x16 aS0, aS1, aA0, aA1;
    #pragma unroll
    for (int i = 0; i < 16; ++i) { aS0[i] = 0.f; aS1[i] = 0.f; aA0[i] = 0.f; aA1[i] = 0.f; }
    float m2 = -3.0e38f, sumS = 0.f, sumA = 0.f;

    const f16* Kbase = K  + ((size_t)(b * L_) * DM_ + h * DK_);
    const f16* Vbase = VT + ((size_t)(b * DM_ + h * DK_) * L_);

    for (int tt = 0; tt < 4; ++tt) {
        const int c0 = (ws * 4 + tt) * 64;

        f16x8 ka[4], kb2[4], vfa[4], vfb[4];
        #pragma unroll
        for (int db = 0; db < 4; ++db) {
            const int dof = db * 16 + 8 * half;
            ka[db]  = *(const f16x8*)&Kbase[(size_t)(c0 + lq) * DM_ + dof];
            kb2[db] = *(const f16x8*)&Kbase[(size_t)(c0 + 32 + lq) * DM_ + dof];
        }
        #pragma unroll
        for (int ks = 0; ks < 4; ++ks) {
            const int coff = c0 + ks * 16 + 8 * half;
            vfa[ks] = *(const f16x8*)&Vbase[(size_t)lq * L_ + coff];
            vfb[ks] = *(const f16x8*)&Vbase[(size_t)(32 + lq) * L_ + coff];
        }

        f32x16 s2a, s2b;
        #pragma unroll
        for (int i = 0; i < 16; ++i) { s2a[i] = 0.f; s2b[i] = 0.f; }
        #pragma unroll
        for (int db = 0; db < 4; ++db) {
            s2a = __builtin_amdgcn_mfma_f32_32x32x16_f16(ka[db],  qh[db], s2a, 0, 0, 0);
            s2b = __builtin_amdgcn_mfma_f32_32x32x16_f16(kb2[db], qh[db], s2b, 0, 0, 0);
        }

        float tm = s2a[0];
        #pragma unroll
        for (int i = 1; i < 16; ++i) tm = fmaxf(tm, s2a[i]);
        #pragma unroll
        for (int i = 0; i < 16; ++i) tm = fmaxf(tm, s2b[i]);
        tm = fmaxf(tm, __shfl_xor(tm, 32));
        if (__any(tm > m2)) {
            const float nm = fmaxf(m2, tm);
            const float sc = exp2f((m2 - nm) * LOG2E_);
            m2 = nm;
            sumS *= sc;
            #pragma unroll
            for (int r = 0; r < 16; ++r) {
                const float s_ = __shfl(sc, (r & 3) + 8 * (r >> 2) + 4 * half);
                aS0[r] *= s_;
                aS1[r] *= s_;
            }
        }

        const float nmL = m2 * LOG2E_;
        #pragma unroll
        for (int sub = 0; sub < 2; ++sub) {
            const f32x16& s2 = sub ? s2b : s2a;
            #pragma unroll
            for (int ksl = 0; ksl < 2; ++ksl) {
                const int rb = ksl * 8;
                float p[8];
                #pragma unroll
                for (int rr = 0; rr < 8; ++rr) {
                    p[rr] = exp2f(fmaf(s2[rb + rr], LOG2E_, -nmL));
                    sumS += p[rr];
                }
                union { unsigned u[4]; f16x8 v; } f;
                f.u[0] = pkrtz(p[0], p[1]);
                f.u[1] = pkrtz(p[2], p[3]);
                f.u[2] = pkrtz(p[4], p[5]);
                f.u[3] = pkrtz(p[6], p[7]);
                plswap(f.u[0], f.u[2]);
                plswap(f.u[1], f.u[3]);
                const int ks = sub * 2 + ksl;
                aS0 = __builtin_amdgcn_mfma_f32_32x32x16_f16(f.v, vfa[ks], aS0, 0, 0, 0);
                aS1 = __builtin_amdgcn_mfma_f32_32x32x16_f16(f.v, vfb[ks], aS1, 0, 0, 0);
            }
        }

        int gl_ = q0w - (c0 + 63);
        int gh_ = c0 - (q0w + 31);
        int dmin = gl_ > gh_ ? gl_ : gh_;
        if (dmin < 0) dmin = 0;
        if (qpw * (float)(dmin * dmin) < 40.0f) {
            #pragma unroll
            for (int sub = 0; sub < 2; ++sub) {
                #pragma unroll
                for (int ksl = 0; ksl < 2; ++ksl) {
                    float a[8];
                    #pragma unroll
                    for (int rr = 0; rr < 8; ++rr) {
                        const int kk = (rr & 3) + 8 * (rr >> 2) + 16 * ksl + 4 * half;
                        const int diff = q - (c0 + sub * 32 + kk);
                        const float fd = (float)diff;
                        const float coef = diff > 0 ? A1 : A0;
                        a[rr] = exp2f(coef * fd * fd);
                        sumA += a[rr];
                    }
                    union { unsigned u[4]; f16x8 v; } f;
                    f.u[0] = pkrtz(a[0], a[1]);
                    f.u[1] = pkrtz(a[2], a[3]);
                    f.u[2] = pkrtz(a[4], a[5]);
                    f.u[3] = pkrtz(a[6], a[7]);
                    plswap(f.u[0], f.u[2]);
                    plswap(f.u[1], f.u[3]);
                    const int ks = sub * 2 + ksl;
                    aA0 = __builtin_amdgcn_mfma_f32_32x32x16_f16(f.v, vfa[ks], aA0, 0, 0, 0);
                    aA1 = __builtin_amdgcn_mfma_f32_32x32x16_f16(f.v, vfb[ks], aA1, 0, 0, 0);
                }
            }
        }
    }

    if (ws == 1) {
        Lm[lane]  = m2;
        Lss[lane] = sumS;
        Lsa[lane] = sumA;
        #pragma unroll
        for (int r = 0; r < 16; ++r) {
            Lacc[0][r][lane] = aS0[r];
            Lacc[1][r][lane] = aS1[r];
            Lacc[2][r][lane] = aA0[r];
            Lacc[3][r][lane] = aA1[r];
        }
    }
    __syncthreads();
    if (ws == 0) {
        const float m2p = Lm[lane];
        const float nm  = fmaxf(m2, m2p);
        const float e0  = exp2f((m2  - nm) * LOG2E_);
        const float e1  = exp2f((m2p - nm) * LOG2E_);
        const float ssm = sumS * e0 + Lss[lane] * e1;
        const float sam = sumA + Lsa[lane];
        const float St  = ssm + __shfl_xor(ssm, 32);
        const float At  = sam + __shfl_xor(sam, 32);
        const float den = sg * St + osg * At + 1e-9f;
        #pragma unroll
        for (int r = 0; r < 16; ++r) {
            const int row = (r & 3) + 8 * (r >> 2) + 4 * half;
            const float dn  = __shfl(den, row);
            const float e0r = __shfl(e0, row);
            const float e1r = __shfl(e1, row);
            const float o0 = (sg * (aS0[r] * e0r + Lacc[0][r][lane] * e1r)
                            + osg * (aA0[r] + Lacc[2][r][lane])) / dn;
            const float o1 = (sg * (aS1[r] * e0r + Lacc[1][r][lane] * e1r)
                            + osg * (aA1[r] + Lacc[3][r][lane])) / dn;
            const size_t base = (size_t)(b * L_ + q0w + row) * DM_ + h * DK_;
            ATT[base + lq]      = (f16)o0;
            ATT[base + 32 + lq] = (f16)o1;
        }
    }
}

// ---------------------------------------------------------------------------
extern "C" void kernel_launch(void* const* d_in, const int* in_sizes, int n_in,
                              void* d_out, int out_size, void* d_ws, size_t ws_size,
                              hipStream_t stream)
{
    (void)in_sizes; (void)n_in; (void)out_size; (void)ws_size;
    const float* query = (const float*)d_in[0];
    const float* key   = (const float*)d_in[1];
    const float* value = (const float*)d_in[2];
    const float* Wq = (const float*)d_in[3];  const float* bq = (const float*)d_in[4];
    const float* Wk = (const float*)d_in[5];  const float* bk = (const float*)d_in[6];
    const float* Wv = (const float*)d_in[7];  const float* bv = (const float*)d_in[8];
    const float* Wg = (const float*)d_in[9];  const float* bg = (const float*)d_in[10];
    const float* lam1 = (const float*)d_in[11];
    const float* Wo = (const float*)d_in[12]; const float* bo = (const float*)d_in[13];

    f16* ws16 = (f16*)d_ws;
    const size_t NR = (size_t)B_ * L_ * DM_;
    f16* Kb  = ws16;
    f16* VTb = ws16 + NR;
    f16* Qb  = ws16 + 2 * NR;
    f16* ATTb = Qb;   // safe alias: each block reads exactly the Q cells it later writes

    gemm_qkv<<<1536, 256, 0, stream>>>(query, key, value, Wq, bq, Wk, bk, Wv, bv,
                                       Qb, Kb, VTb);

    dim3 ga(H_ * B_, L_ / 32);    // (128, 16), 128 threads = 2 split-K waves
    attn_kernel<<<ga, 128, 0, stream>>>(Qb, Kb, VTb, Wg, bg, lam1, ATTb);

    gemm_o<<<512, 256, 0, stream>>>(Qb, Wo, bo, (float*)d_out);
}

// Round 9
// 98.826 us; speedup vs baseline: 1.3972x; 1.3972x over previous
//
#include <hip/hip_runtime.h>
#include <hip/hip_fp16.h>
#include <math.h>

#define B_  16
#define H_  8
#define L_  512
#define DM_ 512
#define DK_ 64
#define LOG2E_ 1.44269504088896340736f
#define NLOG2E_H_ 0.72134752044f   // 0.5 * log2(e)

typedef _Float16 f16;
typedef __attribute__((ext_vector_type(2)))  __fp16   fp16v2;
typedef __attribute__((ext_vector_type(8)))  _Float16 f16x8;
typedef __attribute__((ext_vector_type(16))) float f32x16;

__device__ __forceinline__ unsigned pkrtz(float a, float b) {
    union { fp16v2 v; unsigned u; } cv;
    cv.v = __builtin_amdgcn_cvt_pkrtz(a, b);
    return cv.u;
}
// v_permlane32_swap_b32: x[lanes 32..63] <-> y[lanes 0..31]
__device__ __forceinline__ void plswap(unsigned &x, unsigned &y) {
    asm("v_permlane32_swap_b32 %0, %1" : "+v"(x), "+v"(y));
}

// ---------------------------------------------------------------------------
// MFMA fp16 GEMM core (R7-proven shape):  Y = X[M,512] @ W[512,512]^T + bias
// BM=BN=128, BK=64; 512 threads = 8 waves (2 row-blocks x 4 col-blocks).
// Reg-staged fp32->fp16 conversion; LDS XOR-swizzled; next-tile prefetch.
// row0/col0 passed in (XCD-chunked 1-D grid decode done by caller).
// ---------------------------------------------------------------------------
template<int XF16, int OUTF32, int TRANSOUT>
__device__ __forceinline__ void gemm_core(
    const void* __restrict__ Xv, const float* __restrict__ W,
    const float* __restrict__ bias, void* __restrict__ Yv,
    int row0, int col0, f16* lds)
{
    f16* Al = lds;
    f16* Bl = lds + 128 * 64;

    const int tid   = threadIdx.x;
    const int w     = tid >> 6;
    const int lane  = tid & 63;
    const int lq    = lane & 31;
    const int half_ = lane >> 5;
    const int wr    = w & 1;
    const int wc    = w >> 1;
    const int trow  = tid >> 2;
    const int tseg  = tid & 3;

    f32x16 acc[2];
    #pragma unroll
    for (int rs = 0; rs < 2; ++rs)
        #pragma unroll
        for (int i = 0; i < 16; ++i) acc[rs][i] = 0.f;

    float4 xr[4], wreg[4];
    uint4  xh[2];

    {
        if (XF16) {
            const f16* X = (const f16*)Xv;
            const f16* p = X + (size_t)(row0 + trow) * 512 + tseg * 16;
            xh[0] = *(const uint4*)(p);
            xh[1] = *(const uint4*)(p + 8);
        } else {
            const float* X = (const float*)Xv;
            const float* p = X + (size_t)(row0 + trow) * 512 + tseg * 16;
            xr[0] = *(const float4*)(p);     xr[1] = *(const float4*)(p + 4);
            xr[2] = *(const float4*)(p + 8); xr[3] = *(const float4*)(p + 12);
        }
        const float* q = W + (size_t)(col0 + trow) * 512 + tseg * 16;
        wreg[0] = *(const float4*)(q);     wreg[1] = *(const float4*)(q + 4);
        wreg[2] = *(const float4*)(q + 8); wreg[3] = *(const float4*)(q + 12);
    }

    for (int t = 0; t < 8; ++t) {
        __syncthreads();
        {
            const unsigned base = trow * 128 + tseg * 32;
            const unsigned swz  = (trow & 7) << 4;
            uint4 c0, c1;
            if (XF16) { c0 = xh[0]; c1 = xh[1]; }
            else {
                c0.x = pkrtz(xr[0].x, xr[0].y); c0.y = pkrtz(xr[0].z, xr[0].w);
                c0.z = pkrtz(xr[1].x, xr[1].y); c0.w = pkrtz(xr[1].z, xr[1].w);
                c1.x = pkrtz(xr[2].x, xr[2].y); c1.y = pkrtz(xr[2].z, xr[2].w);
                c1.z = pkrtz(xr[3].x, xr[3].y); c1.w = pkrtz(xr[3].z, xr[3].w);
            }
            *(uint4*)((char*)Al + ((base +  0) ^ swz)) = c0;
            *(uint4*)((char*)Al + ((base + 16) ^ swz)) = c1;
            uint4 d0, d1;
            d0.x = pkrtz(wreg[0].x, wreg[0].y); d0.y = pkrtz(wreg[0].z, wreg[0].w);
            d0.z = pkrtz(wreg[1].x, wreg[1].y); d0.w = pkrtz(wreg[1].z, wreg[1].w);
            d1.x = pkrtz(wreg[2].x, wreg[2].y); d1.y = pkrtz(wreg[2].z, wreg[2].w);
            d1.z = pkrtz(wreg[3].x, wreg[3].y); d1.w = pkrtz(wreg[3].z, wreg[3].w);
            *(uint4*)((char*)Bl + ((base +  0) ^ swz)) = d0;
            *(uint4*)((char*)Bl + ((base + 16) ^ swz)) = d1;
        }
        __syncthreads();

        if (t < 7) {
            const int k0 = (t + 1) * 64;
            if (XF16) {
                const f16* X = (const f16*)Xv;
                const f16* p = X + (size_t)(row0 + trow) * 512 + k0 + tseg * 16;
                xh[0] = *(const uint4*)(p);
                xh[1] = *(const uint4*)(p + 8);
            } else {
                const float* X = (const float*)Xv;
                const float* p = X + (size_t)(row0 + trow) * 512 + k0 + tseg * 16;
                xr[0] = *(const float4*)(p);     xr[1] = *(const float4*)(p + 4);
                xr[2] = *(const float4*)(p + 8); xr[3] = *(const float4*)(p + 12);
            }
            const float* q = W + (size_t)(col0 + trow) * 512 + k0 + tseg * 16;
            wreg[0] = *(const float4*)(q);     wreg[1] = *(const float4*)(q + 4);
            wreg[2] = *(const float4*)(q + 8); wreg[3] = *(const float4*)(q + 12);
        }

        const int ra0 = wr * 64 + lq;
        const int ra1 = wr * 64 + 32 + lq;
        const int rbc = wc * 32 + lq;
        #pragma unroll
        for (int ks = 0; ks < 4; ++ks) {
            const unsigned koff = ks * 32 + half_ * 16;
            f16x8 a0, a1, bf;
            if (TRANSOUT) {
                a0 = *(const f16x8*)((char*)Bl + ((ra0 * 128 + koff) ^ ((ra0 & 7) << 4)));
                a1 = *(const f16x8*)((char*)Bl + ((ra1 * 128 + koff) ^ ((ra1 & 7) << 4)));
                bf = *(const f16x8*)((char*)Al + ((rbc * 128 + koff) ^ ((rbc & 7) << 4)));
            } else {
                a0 = *(const f16x8*)((char*)Al + ((ra0 * 128 + koff) ^ ((ra0 & 7) << 4)));
                a1 = *(const f16x8*)((char*)Al + ((ra1 * 128 + koff) ^ ((ra1 & 7) << 4)));
                bf = *(const f16x8*)((char*)Bl + ((rbc * 128 + koff) ^ ((rbc & 7) << 4)));
            }
            acc[0] = __builtin_amdgcn_mfma_f32_32x32x16_f16(a0, bf, acc[0], 0, 0, 0);
            acc[1] = __builtin_amdgcn_mfma_f32_32x32x16_f16(a1, bf, acc[1], 0, 0, 0);
        }
    }

    if (TRANSOUT) {
        // acc[rs][r] = Y^T[n = col0+wr*64+rs*32+crow][l = row0+wc*32+lq]
        const int lg = row0 + wc * 32 + lq;
        const int bI = lg >> 9, ll = lg & 511;
        #pragma unroll
        for (int rs = 0; rs < 2; ++rs) {
            #pragma unroll
            for (int r = 0; r < 16; ++r) {
                const int n = col0 + wr * 64 + rs * 32 + (r & 3) + 8 * (r >> 2) + 4 * half_;
                const float v = acc[rs][r] + bias[n];
                ((f16*)Yv)[((size_t)(bI * 512 + n)) * 512 + ll] = (f16)v;
            }
        }
    } else {
        const float bv = bias[col0 + wc * 32 + lq];
        #pragma unroll
        for (int rs = 0; rs < 2; ++rs) {
            #pragma unroll
            for (int r = 0; r < 16; ++r) {
                const int row = row0 + wc * 0 + wr * 64 + rs * 32 + (r & 3) + 8 * (r >> 2) + 4 * half_;
                const float v = acc[rs][r] + bv;
                const size_t off = (size_t)row * 512 + col0 + wc * 32 + lq;
                if (OUTF32) ((float*)Yv)[off] = v;
                else        ((f16*)Yv)[off]   = (f16)v;
            }
        }
    }
}

// fused Q/K/V projections, XCD-chunked 1-D grid: 768 blocks.
// wg -> xcd = wg&7; i = wg>>3 (0..95); col = i&3; p = i>>2 (0..23);
// panel = xcd*24 + p (0..191); z = panel>>6; y = panel&63.
// All 4 col-blocks of an X panel run consecutively on ONE XCD.
__global__ __launch_bounds__(512) void gemm_qkv(
    const float* __restrict__ query, const float* __restrict__ key,
    const float* __restrict__ value,
    const float* __restrict__ Wq, const float* __restrict__ bq,
    const float* __restrict__ Wk, const float* __restrict__ bk,
    const float* __restrict__ Wv, const float* __restrict__ bv,
    void* __restrict__ Qb, void* __restrict__ Kb, void* __restrict__ VT)
{
    __shared__ f16 lds[2 * 128 * 64];
    const int wg  = blockIdx.x;
    const int xcd = wg & 7;
    const int i   = wg >> 3;
    const int col = i & 3;
    const int p   = i >> 2;
    const int pg  = xcd * 24 + p;       // 0..191
    const int z   = pg >> 6;
    const int y   = pg & 63;
    const int row0 = y * 128, col0 = col * 128;

    if (z == 0)      gemm_core<0, 0, 0>(query, Wq, bq, Qb, row0, col0, lds);
    else if (z == 1) gemm_core<0, 0, 0>(key,   Wk, bk, Kb, row0, col0, lds);
    else             gemm_core<0, 0, 1>(value, Wv, bv, VT, row0, col0, lds);
}

// output GEMM, XCD-chunked 1-D grid: 256 blocks.
// xcd = wg&7; i = wg>>3 (0..31); col = i&3; y = xcd*8 + (i>>2).
__global__ __launch_bounds__(512) void gemm_o(
    const void* __restrict__ X, const float* __restrict__ Wo,
    const float* __restrict__ bo, void* __restrict__ Y)
{
    __shared__ f16 lds[2 * 128 * 64];
    const int wg  = blockIdx.x;
    const int xcd = wg & 7;
    const int i   = wg >> 3;
    const int col = i & 3;
    const int y   = xcd * 8 + (i >> 2);
    gemm_core<1, 1, 0>(X, Wo, bo, Y, y * 128, col * 128, lds);
}

// ---------------------------------------------------------------------------
// Split-K zero-staging MFMA flash attention (unchanged).
// ---------------------------------------------------------------------------
__global__ __launch_bounds__(128) void attn_kernel(
    const f16* __restrict__ Q, const f16* __restrict__ K,
    const f16* __restrict__ VT, const float* __restrict__ Wg,
    const float* __restrict__ bg, const float* __restrict__ lam1,
    f16* __restrict__ ATT)
{
    __shared__ float Lm[64], Lss[64], Lsa[64];
    __shared__ float Lacc[4][16][64];

    const int tid  = threadIdx.x;
    const int ws   = tid >> 6;        // split-K wave id (0,1)
    const int lane = tid & 63;
    const int lq   = lane & 31;
    const int half = lane >> 5;
    const int bh   = blockIdx.x;      // same bh -> same XCD
    const int b    = bh >> 3;
    const int h    = bh & 7;
    const int q0w  = blockIdx.y * 32;
    const int q    = q0w + lq;

    const float sg  = 1.f / (1.f + __expf(-lam1[0]));
    const float osg = 1.f - sg;

    f16x8 qh[4];
    {
        const f16* qrow = Q + ((size_t)(b * L_ + q) * DM_ + h * DK_);
        #pragma unroll
        for (int db = 0; db < 4; ++db)
            qh[db] = *(const f16x8*)&qrow[db * 16 + 8 * half];
    }

    float A0, A1, qpw;
    {
        float g0 = 0.f, g1 = 0.f;
        #pragma unroll
        for (int db = 0; db < 4; ++db)
            #pragma unroll
            for (int j = 0; j < 8; ++j) {
                const int d = db * 16 + 8 * half + j;
                const float qv = (float)qh[db][j];
                g0 = fmaf(qv, Wg[d], g0);
                g1 = fmaf(qv, Wg[64 + d], g1);
            }
        g0 += __shfl_xor(g0, 32);
        g1 += __shfl_xor(g1, 32);
        g0 += bg[0];
        g1 += bg[1];
        const float t0 = fabsf(g0) + 1.f, t1 = fabsf(g1) + 1.f;
        const float p0 = 1.f / (t0 * t0), p1 = 1.f / (t1 * t1);
        A0 = -NLOG2E_H_ * p0;       // c >= q (triu)
        A1 = -NLOG2E_H_ * p1;       // c <  q (tril)
        float mn = NLOG2E_H_ * fminf(p0, p1);
        #pragma unroll
        for (int off = 1; off < 64; off <<= 1) mn = fminf(mn, __shfl_xor(mn, off));
        qpw = mn;
    }

    f32x16 aS0, aS1, aA0, aA1;
    #pragma unroll
    for (int i = 0; i < 16; ++i) { aS0[i] = 0.f; aS1[i] = 0.f; aA0[i] = 0.f; aA1[i] = 0.f; }
    float m2 = -3.0e38f, sumS = 0.f, sumA = 0.f;

    const f16* Kbase = K  + ((size_t)(b * L_) * DM_ + h * DK_);
    const f16* Vbase = VT + ((size_t)(b * DM_ + h * DK_) * L_);

    for (int tt = 0; tt < 4; ++tt) {
        const int c0 = (ws * 4 + tt) * 64;

        f16x8 ka[4], kb2[4], vfa[4], vfb[4];
        #pragma unroll
        for (int db = 0; db < 4; ++db) {
            const int dof = db * 16 + 8 * half;
            ka[db]  = *(const f16x8*)&Kbase[(size_t)(c0 + lq) * DM_ + dof];
            kb2[db] = *(const f16x8*)&Kbase[(size_t)(c0 + 32 + lq) * DM_ + dof];
        }
        #pragma unroll
        for (int ks = 0; ks < 4; ++ks) {
            const int coff = c0 + ks * 16 + 8 * half;
            vfa[ks] = *(const f16x8*)&Vbase[(size_t)lq * L_ + coff];
            vfb[ks] = *(const f16x8*)&Vbase[(size_t)(32 + lq) * L_ + coff];
        }

        f32x16 s2a, s2b;
        #pragma unroll
        for (int i = 0; i < 16; ++i) { s2a[i] = 0.f; s2b[i] = 0.f; }
        #pragma unroll
        for (int db = 0; db < 4; ++db) {
            s2a = __builtin_amdgcn_mfma_f32_32x32x16_f16(ka[db],  qh[db], s2a, 0, 0, 0);
            s2b = __builtin_amdgcn_mfma_f32_32x32x16_f16(kb2[db], qh[db], s2b, 0, 0, 0);
        }

        float tm = s2a[0];
        #pragma unroll
        for (int i = 1; i < 16; ++i) tm = fmaxf(tm, s2a[i]);
        #pragma unroll
        for (int i = 0; i < 16; ++i) tm = fmaxf(tm, s2b[i]);
        tm = fmaxf(tm, __shfl_xor(tm, 32));
        if (__any(tm > m2)) {
            const float nm = fmaxf(m2, tm);
            const float sc = exp2f((m2 - nm) * LOG2E_);
            m2 = nm;
            sumS *= sc;
            #pragma unroll
            for (int r = 0; r < 16; ++r) {
                const float s_ = __shfl(sc, (r & 3) + 8 * (r >> 2) + 4 * half);
                aS0[r] *= s_;
                aS1[r] *= s_;
            }
        }

        const float nmL = m2 * LOG2E_;
        #pragma unroll
        for (int sub = 0; sub < 2; ++sub) {
            const f32x16& s2 = sub ? s2b : s2a;
            #pragma unroll
            for (int ksl = 0; ksl < 2; ++ksl) {
                const int rb = ksl * 8;
                float p[8];
                #pragma unroll
                for (int rr = 0; rr < 8; ++rr) {
                    p[rr] = exp2f(fmaf(s2[rb + rr], LOG2E_, -nmL));
                    sumS += p[rr];
                }
                union { unsigned u[4]; f16x8 v; } f;
                f.u[0] = pkrtz(p[0], p[1]);
                f.u[1] = pkrtz(p[2], p[3]);
                f.u[2] = pkrtz(p[4], p[5]);
                f.u[3] = pkrtz(p[6], p[7]);
                plswap(f.u[0], f.u[2]);
                plswap(f.u[1], f.u[3]);
                const int ks = sub * 2 + ksl;
                aS0 = __builtin_amdgcn_mfma_f32_32x32x16_f16(f.v, vfa[ks], aS0, 0, 0, 0);
                aS1 = __builtin_amdgcn_mfma_f32_32x32x16_f16(f.v, vfb[ks], aS1, 0, 0, 0);
            }
        }

        int gl_ = q0w - (c0 + 63);
        int gh_ = c0 - (q0w + 31);
        int dmin = gl_ > gh_ ? gl_ : gh_;
        if (dmin < 0) dmin = 0;
        if (qpw * (float)(dmin * dmin) < 40.0f) {
            #pragma unroll
            for (int sub = 0; sub < 2; ++sub) {
                #pragma unroll
                for (int ksl = 0; ksl < 2; ++ksl) {
                    float a[8];
                    #pragma unroll
                    for (int rr = 0; rr < 8; ++rr) {
                        const int kk = (rr & 3) + 8 * (rr >> 2) + 16 * ksl + 4 * half;
                        const int diff = q - (c0 + sub * 32 + kk);
                        const float fd = (float)diff;
                        const float coef = diff > 0 ? A1 : A0;
                        a[rr] = exp2f(coef * fd * fd);
                        sumA += a[rr];
                    }
                    union { unsigned u[4]; f16x8 v; } f;
                    f.u[0] = pkrtz(a[0], a[1]);
                    f.u[1] = pkrtz(a[2], a[3]);
                    f.u[2] = pkrtz(a[4], a[5]);
                    f.u[3] = pkrtz(a[6], a[7]);
                    plswap(f.u[0], f.u[2]);
                    plswap(f.u[1], f.u[3]);
                    const int ks = sub * 2 + ksl;
                    aA0 = __builtin_amdgcn_mfma_f32_32x32x16_f16(f.v, vfa[ks], aA0, 0, 0, 0);
                    aA1 = __builtin_amdgcn_mfma_f32_32x32x16_f16(f.v, vfb[ks], aA1, 0, 0, 0);
                }
            }
        }
    }

    if (ws == 1) {
        Lm[lane]  = m2;
        Lss[lane] = sumS;
        Lsa[lane] = sumA;
        #pragma unroll
        for (int r = 0; r < 16; ++r) {
            Lacc[0][r][lane] = aS0[r];
            Lacc[1][r][lane] = aS1[r];
            Lacc[2][r][lane] = aA0[r];
            Lacc[3][r][lane] = aA1[r];
        }
    }
    __syncthreads();
    if (ws == 0) {
        const float m2p = Lm[lane];
        const float nm  = fmaxf(m2, m2p);
        const float e0  = exp2f((m2  - nm) * LOG2E_);
        const float e1  = exp2f((m2p - nm) * LOG2E_);
        const float ssm = sumS * e0 + Lss[lane] * e1;
        const float sam = sumA + Lsa[lane];
        const float St  = ssm + __shfl_xor(ssm, 32);
        const float At  = sam + __shfl_xor(sam, 32);
        const float den = sg * St + osg * At + 1e-9f;
        #pragma unroll
        for (int r = 0; r < 16; ++r) {
            const int row = (r & 3) + 8 * (r >> 2) + 4 * half;
            const float dn  = __shfl(den, row);
            const float e0r = __shfl(e0, row);
            const float e1r = __shfl(e1, row);
            const float o0 = (sg * (aS0[r] * e0r + Lacc[0][r][lane] * e1r)
                            + osg * (aA0[r] + Lacc[2][r][lane])) / dn;
            const float o1 = (sg * (aS1[r] * e0r + Lacc[1][r][lane] * e1r)
                            + osg * (aA1[r] + Lacc[3][r][lane])) / dn;
            const size_t base = (size_t)(b * L_ + q0w + row) * DM_ + h * DK_;
            ATT[base + lq]      = (f16)o0;
            ATT[base + 32 + lq] = (f16)o1;
        }
    }
}

// ---------------------------------------------------------------------------
extern "C" void kernel_launch(void* const* d_in, const int* in_sizes, int n_in,
                              void* d_out, int out_size, void* d_ws, size_t ws_size,
                              hipStream_t stream)
{
    (void)in_sizes; (void)n_in; (void)out_size; (void)ws_size;
    const float* query = (const float*)d_in[0];
    const float* key   = (const float*)d_in[1];
    const float* value = (const float*)d_in[2];
    const float* Wq = (const float*)d_in[3];  const float* bq = (const float*)d_in[4];
    const float* Wk = (const float*)d_in[5];  const float* bk = (const float*)d_in[6];
    const float* Wv = (const float*)d_in[7];  const float* bv = (const float*)d_in[8];
    const float* Wg = (const float*)d_in[9];  const float* bg = (const float*)d_in[10];
    const float* lam1 = (const float*)d_in[11];
    const float* Wo = (const float*)d_in[12]; const float* bo = (const float*)d_in[13];

    f16* ws16 = (f16*)d_ws;
    const size_t NR = (size_t)B_ * L_ * DM_;
    f16* Kb  = ws16;
    f16* VTb = ws16 + NR;
    f16* Qb  = ws16 + 2 * NR;
    f16* ATTb = Qb;   // safe alias: each block reads exactly the Q cells it later writes

    gemm_qkv<<<768, 512, 0, stream>>>(query, key, value, Wq, bq, Wk, bk, Wv, bv,
                                      Qb, Kb, VTb);

    dim3 ga(H_ * B_, L_ / 32);    // (128, 16), 128 threads = 2 split-K waves
    attn_kernel<<<ga, 128, 0, stream>>>(Qb, Kb, VTb, Wg, bg, lam1, ATTb);

    gemm_o<<<256, 512, 0, stream>>>(Qb, Wo, bo, (float*)d_out);
}